// Round 10
// baseline (157.019 us; speedup 1.0000x reference)
//
#include <hip/hip_runtime.h>

#define HID    128
#define VOCAB  1000
#define N_CAT  200000
#define N_CONT 150000
#define N_TXN  150000
#define F_TXN  371
#define NSTEP  12                            // 12*32 = 384 >= 371
#define OUT_TXN_BASE (N_CAT + N_CONT)

#define SLAB_ROWS   16
#define SLAB_F32    (SLAB_ROWS * F_TXN)      // 5936 floats = 1484 x 16B chunks exactly
#define SLAB_CHUNKS (SLAB_F32 / 4)           // 1484
#define LROW        392                      // LDS row stride in shorts
#define PADC        (LROW - F_TXN - 8)       // 13 zeroed pad cols (371..383)
#define SLAB_SHORTS (SLAB_ROWS * LROW)       // 6272 shorts = 12544 B
#define NSLAB       (N_TXN / SLAB_ROWS)      // 9375 exactly; NSLAB*SLAB_F32 == A elems
#define PBLK        768                      // persistent txn blocks (3/CU)

#define CAT_BLOCKS  (N_CAT / 8)              // 25000
#define CONT_BLOCKS (N_CONT / 8)             // 18750
#define GRID_TOTAL  (PBLK + CAT_BLOCKS + CONT_BLOCKS)

typedef __attribute__((ext_vector_type(4))) float f32x4;
typedef __attribute__((ext_vector_type(8))) short bf16x8;

__device__ __forceinline__ unsigned cvt_pk(float lo, float hi) {
    unsigned r;
    asm("v_cvt_pk_bf16_f32 %0, %1, %2" : "=v"(r) : "v"(lo), "v"(hi));
    return r;
}

union BFrag { bf16x8 v; unsigned u[4]; };

// One launch: blocks [0, PBLK) = persistent txn GEMM; the rest = cat/cont
// streaming. They co-run, so catcont's pure-BW phase fills the memory pipes
// the latency-bound GEMM leaves idle.
__global__ __launch_bounds__(256) void fused_kernel(
    const float* __restrict__ tables, const int* __restrict__ tids, const int* __restrict__ vids,
    const float* __restrict__ cw, const float* __restrict__ cb,
    const float* __restrict__ vals, const int* __restrict__ ctids,
    const float* __restrict__ txn_w, const float* __restrict__ txn_b,
    const float* __restrict__ feats, float* __restrict__ out)
{
    __shared__ __align__(16) unsigned short Alds[2 * SLAB_SHORTS];   // 25088 B

    if (blockIdx.x >= PBLK) {
        // ================= cat / cont streaming =================
        int bid = blockIdx.x - PBLK;
        if (bid < CAT_BLOCKS) {
            int tid = bid * 256 + threadIdx.x;
            int row = tid >> 5;
            int h   = (tid & 31) << 2;
            long src = ((long)tids[row] * VOCAB + vids[row]) * HID + h;
            *reinterpret_cast<f32x4*>(out + (long)row * HID + h) =
                *reinterpret_cast<const f32x4*>(tables + src);
        } else {
            int tid = (bid - CAT_BLOCKS) * 256 + threadIdx.x;
            int row = tid >> 5;
            int h   = (tid & 31) << 2;
            int ty  = ctids[row];
            float v = vals[row];
            f32x4 wv = *reinterpret_cast<const f32x4*>(cw + ty * HID + h);
            f32x4 bv = *reinterpret_cast<const f32x4*>(cb + ty * HID + h);
            f32x4 r  = v * wv + bv;
            *reinterpret_cast<f32x4*>(out + (long)(N_CAT + row) * HID + h) = r;
        }
        return;
    }

    // ================= persistent txn GEMM =================
    const int t    = threadIdx.x;
    const int lane = t & 63;
    const int w    = t >> 6;
    const int r16  = lane & 15;
    const int kg   = lane >> 4;          // k-group: k = kg*8 + j
    const int bid  = blockIdx.x;

    // ---- B fragments straight from txn_w (f32, L2-hot 190 KB), once per block ----
    BFrag Bf0[NSTEP], Bf1[NSTEP];
    const int c0 = w * 32 + r16, c1 = c0 + 16;
    const float bv0 = txn_b[c0], bv1 = txn_b[c1];
    #pragma unroll
    for (int s = 0; s < NSTEP; ++s) {
        #pragma unroll
        for (int h = 0; h < 4; ++h) {
            int k = s * 32 + kg * 8 + h * 2;
            float w0 = (k     < F_TXN) ? txn_w[(long)k * HID + c0] : 0.f;
            float w1 = (k + 1 < F_TXN) ? txn_w[(long)(k + 1) * HID + c0] : 0.f;
            Bf0[s].u[h] = cvt_pk(w0, w1);
            float x0 = (k     < F_TXN) ? txn_w[(long)k * HID + c1] : 0.f;
            float x1 = (k + 1 < F_TXN) ? txn_w[(long)(k + 1) * HID + c1] : 0.f;
            Bf1[s].u[h] = cvt_pk(x0, x1);
        }
    }

    // ---- fixed staging geometry: thread t owns 16B chunks q = i*256+t ----
    bool sval[6];
    unsigned wa0[6], wa1[6];                 // packed LDS short-addresses
    #pragma unroll
    for (int i = 0; i < 6; ++i) {
        int q = i * 256 + t;
        sval[i] = (q < SLAB_CHUNKS);
        int qq = sval[i] ? q : 0;
        unsigned a[4];
        #pragma unroll
        for (int j = 0; j < 4; ++j) {
            int e   = qq * 4 + j;            // float index within slab
            int r   = e / F_TXN;
            int col = e - r * F_TXN;
            a[j] = (unsigned)(r * LROW + col);
        }
        wa0[i] = a[0] | (a[1] << 16);
        wa1[i] = a[2] | (a[3] << 16);
    }

    // ---- zero pad cols 371..383 (read at s=11; keeps NaN out of MFMA) ----
    for (int z = t; z < 2 * SLAB_ROWS * PADC; z += 256) {
        int b  = z / (SLAB_ROWS * PADC);
        int rm = z - b * (SLAB_ROWS * PADC);
        int r  = rm / PADC;
        int cc = rm - r * PADC;
        Alds[b * SLAB_SHORTS + r * LROW + F_TXN + cc] = 0;
    }

    f32x4 ar[6];
    auto gload = [&](int sl) {
        size_t S0 = (size_t)sl * SLAB_F32;   // 16B-aligned; slab grid covers A exactly
        #pragma unroll
        for (int i = 0; i < 6; ++i)
            if (sval[i])
                ar[i] = *reinterpret_cast<const f32x4*>(feats + S0 + (size_t)(i * 256 + t) * 4);
    };
    auto swrite = [&](int buf) {
        unsigned short* dst = Alds + buf * SLAB_SHORTS;
        #pragma unroll
        for (int i = 0; i < 6; ++i)
            if (sval[i]) {
                unsigned lo = cvt_pk(ar[i][0], ar[i][1]);   // 1 VALU per pair
                unsigned hi = cvt_pk(ar[i][2], ar[i][3]);
                dst[wa0[i] & 0xffffu] = (unsigned short)lo;
                dst[wa0[i] >> 16]     = (unsigned short)(lo >> 16);
                dst[wa1[i] & 0xffffu] = (unsigned short)hi;
                dst[wa1[i] >> 16]     = (unsigned short)(hi >> 16);
            }
    };

    // prologue: LDS[0] = slab bid
    gload(bid);
    swrite(0);
    __syncthreads();

    int cur = 0;
    #pragma unroll 1
    for (int sl = bid; sl < NSLAB; sl += PBLK) {
        int  nxt      = sl + PBLK;
        bool have_nxt = (nxt < NSLAB);
        if (have_nxt) gload(nxt);             // latency hides under compute

        f32x4 acc0 = f32x4{0.f, 0.f, 0.f, 0.f};
        f32x4 acc1 = f32x4{0.f, 0.f, 0.f, 0.f};
        const unsigned short* Ar = Alds + cur * SLAB_SHORTS + r16 * LROW;
        #pragma unroll
        for (int s = 0; s < NSTEP; ++s) {     // uniform-bank b128 reads
            bf16x8 af = *reinterpret_cast<const bf16x8*>(Ar + s * 32 + kg * 8);
            acc0 = __builtin_amdgcn_mfma_f32_16x16x32_bf16(af, Bf0[s].v, acc0, 0, 0, 0);
            acc1 = __builtin_amdgcn_mfma_f32_16x16x32_bf16(af, Bf1[s].v, acc1, 0, 0, 0);
        }

        if (have_nxt) swrite(cur ^ 1);        // waits only this iter's 6 loads

        long R0 = (long)sl * SLAB_ROWS + kg * 4;  // C stores fly across the barrier
        #pragma unroll
        for (int j = 0; j < 4; ++j) {
            float* o = out + (OUT_TXN_BASE + R0 + j) * HID;
            o[c0]      = acc0[j] + bv0;
            o[c0 + 16] = acc1[j] + bv1;
        }

        asm volatile("s_waitcnt lgkmcnt(0)" ::: "memory");   // LDS writes visible
        __builtin_amdgcn_s_barrier();          // raw barrier: no vmcnt drain
        __builtin_amdgcn_sched_barrier(0);
        cur ^= 1;
    }
}

extern "C" void kernel_launch(void* const* d_in, const int* in_sizes, int n_in,
                              void* d_out, int out_size, void* d_ws, size_t ws_size,
                              hipStream_t stream) {
    const float* cat_tables    = (const float*)d_in[0];
    const float* cont_w        = (const float*)d_in[1];
    const float* cont_b        = (const float*)d_in[2];
    const float* txn_w         = (const float*)d_in[3];
    const float* txn_b         = (const float*)d_in[4];
    const float* txn_feats     = (const float*)d_in[5];
    const float* cont_values   = (const float*)d_in[6];
    const int*   cat_type_ids  = (const int*)d_in[7];
    const int*   cat_value_ids = (const int*)d_in[8];
    const int*   cont_type_ids = (const int*)d_in[9];
    float* out = (float*)d_out;

    fused_kernel<<<GRID_TOTAL, 256, 0, stream>>>(
        cat_tables, cat_type_ids, cat_value_ids,
        cont_w, cont_b, cont_values, cont_type_ids,
        txn_w, txn_b, txn_feats, out);
}

// Round 12
// 135.376 us; speedup vs baseline: 1.1599x; 1.1599x over previous
//
#include <hip/hip_runtime.h>

#define HID    128
#define VOCAB  1000
#define N_CAT  200000
#define N_CONT 150000
#define N_TXN  150000
#define F_TXN  371
#define KP     384
#define NSTEP  12                            // 12*32 = 384 >= 371
#define OUT_TXN_BASE (N_CAT + N_CONT)

#define SLAB_ROWS   16
#define SLAB_F32    (SLAB_ROWS * F_TXN)      // 5936 floats = 1484 x 16B chunks
#define SLAB_CHUNKS (SLAB_F32 / 4)           // 1484
#define LROW        392                      // A LDS row stride (shorts)
#define SLAB_SHORTS (SLAB_ROWS * LROW)       // 6272
#define NSLAB       (N_TXN / SLAB_ROWS)      // 9375 exactly
#define A_ELEMS     ((size_t)N_TXN * F_TXN)
#define B_SHORTS    (HID * KP)               // 49152 shorts (96 KB)
#define BCOPY_IT    (B_SHORTS / (256 * 8))   // 24 cooperative copy iterations
#define TBLK        256                      // 1 block per CU
#define GW          (TBLK * 4)               // 1024 independent waves

static_assert(BCOPY_IT * 256 * 8 == B_SHORTS, "B copy must cover the whole image");

typedef __attribute__((ext_vector_type(4))) float f32x4;
typedef __attribute__((ext_vector_type(8))) short bf16x8;

__device__ __forceinline__ unsigned short f2bf(float x) {
    union { float f; unsigned u; } c; c.f = x;
    unsigned r = c.u + 0x7FFF + ((c.u >> 16) & 1);   // RNE
    return (unsigned short)(r >> 16);
}

__device__ __forceinline__ unsigned cvt_pk(float lo, float hi) {
    unsigned r;
    asm("v_cvt_pk_bf16_f32 %0, %1, %2" : "=v"(r) : "v"(lo), "v"(hi));
    return r;
}

// ---- producer: XOR-swizzled B image. element (col,k) at
//      col*KP + ((k>>3) ^ (col&7))*8 + (k&7)   (zero-padded k>=371) ----
__global__ void bt_kernel(const float* __restrict__ w, unsigned short* __restrict__ btx) {
    int col = blockIdx.x;          // 0..127
    int k   = threadIdx.x;         // 0..383
    float v = (k < F_TXN) ? w[(long)k * HID + col] : 0.f;
    int addr = col * KP + (((k >> 3) ^ (col & 7)) << 3) + (k & 7);
    btx[addr] = f2bf(v);
}

// ---- fused cat gather + cont linear (validated ~BW floor) ----
#define CAT_BLOCKS  (N_CAT / 8)
#define CONT_BLOCKS (N_CONT / 8)
__global__ __launch_bounds__(256) void catcont_kernel(
    const float* __restrict__ tables, const int* __restrict__ tids, const int* __restrict__ vids,
    const float* __restrict__ w, const float* __restrict__ b,
    const float* __restrict__ vals, const int* __restrict__ ctids,
    float* __restrict__ out)
{
    int bid = blockIdx.x;
    if (bid < CAT_BLOCKS) {
        int tid = bid * 256 + threadIdx.x;
        int row = tid >> 5;
        int h   = (tid & 31) << 2;
        long src = ((long)tids[row] * VOCAB + vids[row]) * HID + h;
        *reinterpret_cast<f32x4*>(out + (long)row * HID + h) =
            *reinterpret_cast<const f32x4*>(tables + src);
    } else {
        int tid = (bid - CAT_BLOCKS) * 256 + threadIdx.x;
        int row = tid >> 5;
        int h   = (tid & 31) << 2;
        int t   = ctids[row];
        float v = vals[row];
        f32x4 wv = *reinterpret_cast<const f32x4*>(w + t * HID + h);
        f32x4 bv = *reinterpret_cast<const f32x4*>(b + t * HID + h);
        f32x4 r  = v * wv + bv;
        *reinterpret_cast<f32x4*>(out + (long)(N_CAT + row) * HID + h) = r;
    }
}

// ---- txn GEMM: B-stationary in LDS, barrier-free independent waves ----
// 1 block/CU. LDS = B image (96 KB, loaded once) + 4 private A-slab regions.
// Each wave: 16 rows x 128 cols per slab, zero barriers in the loop.
__global__ __launch_bounds__(256) void txn_bstat_kernel(
    const float* __restrict__ feats, const unsigned short* __restrict__ btx,
    const float* __restrict__ bias, float* __restrict__ out)
{
    __shared__ __align__(16) unsigned short LDS[B_SHORTS + 4 * SLAB_SHORTS]; // 145 KB

    const int t    = threadIdx.x;
    const int lane = t & 63;
    const int w    = t >> 6;
    const int r16  = lane & 15;
    const int kg   = lane >> 4;
    unsigned short* Bs = LDS;                              // shared, read-only after init
    unsigned short* Aw = LDS + B_SHORTS + w * SLAB_SHORTS; // wave-private

    // ---- cooperative B copy: FULL image, 24 x 256 x 8 shorts ----
    #pragma unroll
    for (int i = 0; i < BCOPY_IT; ++i) {
        int off = (i * 256 + t) * 8;
        *reinterpret_cast<bf16x8*>(Bs + off) =
            *reinterpret_cast<const bf16x8*>(btx + off);
    }
    // ---- zero own A pad cols 371..383 (read at s=11; B=0 there too) ----
    for (int z = lane; z < SLAB_ROWS * 13; z += 64) {
        int r = z / 13, c = z - 13 * r;
        Aw[r * LROW + F_TXN + c] = 0;
    }
    float bv[8];
    #pragma unroll
    for (int cf = 0; cf < 8; ++cf) bv[cf] = bias[cf * 16 + r16];

    const int gw = blockIdx.x * 4 + w;     // global wave id, < 1024 <= NSLAB

    f32x4 ar[24];
    auto gload = [&](int sl) {
        size_t S0 = (size_t)sl * SLAB_F32;
        #pragma unroll
        for (int i = 0; i < 24; ++i) {     // 1 KB contiguous per wave-instr
            size_t ge = S0 + (size_t)((i * 64 + lane) * 4);
            if (ge > A_ELEMS - 4) ge = A_ELEMS - 4;
            ar[i] = *reinterpret_cast<const f32x4*>(feats + ge);
        }
    };
    auto swrite = [&]() {
        #pragma unroll
        for (int i = 0; i < 24; ++i) {
            int c = i * 64 + lane;
            if (c < SLAB_CHUNKS) {         // exec-masked ds_write: safe (not DMA)
                int e  = c * 4;
                int r  = e / F_TXN;        // magic-div
                int c0 = e - r * F_TXN;
                int a  = r * LROW + c0;
                unsigned lo = cvt_pk(ar[i][0], ar[i][1]);
                unsigned hi = cvt_pk(ar[i][2], ar[i][3]);
                // straddle: elem j with c0+j>=371 belongs to next row (+21 shorts)
                Aw[a]                                      = (unsigned short)lo;
                Aw[a + 1 + ((c0 + 1 >= F_TXN) ? 21 : 0)]   = (unsigned short)(lo >> 16);
                Aw[a + 2 + ((c0 + 2 >= F_TXN) ? 21 : 0)]   = (unsigned short)hi;
                Aw[a + 3 + ((c0 + 3 >= F_TXN) ? 21 : 0)]   = (unsigned short)(hi >> 16);
            }
        }
    };

    gload(gw);
    __syncthreads();                       // B image + pads visible; ONLY barrier
    swrite();
    asm volatile("s_waitcnt lgkmcnt(0)" ::: "memory");
    __builtin_amdgcn_sched_barrier(0);

    #pragma unroll 1
    for (int sl = gw; sl < NSLAB; ) {
        int  nxt  = sl + GW;
        bool more = (nxt < NSLAB);         // wave-uniform
        if (more) gload(nxt);              // in flight under this slab's compute

        f32x4 acc[8];
        #pragma unroll
        for (int cf = 0; cf < 8; ++cf) acc[cf] = f32x4{0.f, 0.f, 0.f, 0.f};

        const unsigned short* Ar = Aw + r16 * LROW;
        #pragma unroll
        for (int s = 0; s < NSTEP; ++s) {
            bf16x8 af = *reinterpret_cast<const bf16x8*>(Ar + s * 32 + kg * 8);
            const int gsw = (((4 * s + kg) ^ (r16 & 7)) << 3);   // B bank swizzle
            #pragma unroll
            for (int cf = 0; cf < 8; ++cf) {
                bf16x8 bf = *reinterpret_cast<const bf16x8*>(
                    Bs + (cf * 16 + r16) * KP + gsw);
                acc[cf] = __builtin_amdgcn_mfma_f32_16x16x32_bf16(af, bf, acc[cf], 0, 0, 0);
            }
        }

        long R0 = (long)sl * SLAB_ROWS + kg * 4;   // stores after loads: never block them
        #pragma unroll
        for (int j = 0; j < 4; ++j) {
            float* o = out + (OUT_TXN_BASE + R0 + j) * HID + r16;
            #pragma unroll
            for (int cf = 0; cf < 8; ++cf) o[cf * 16] = acc[cf][j] + bv[cf];
        }

        if (!more) break;
        swrite();                          // vmcnt waits only the 24 loads (oldest)
        asm volatile("s_waitcnt lgkmcnt(0)" ::: "memory");
        __builtin_amdgcn_sched_barrier(0);
        sl = nxt;
    }
}

extern "C" void kernel_launch(void* const* d_in, const int* in_sizes, int n_in,
                              void* d_out, int out_size, void* d_ws, size_t ws_size,
                              hipStream_t stream) {
    const float* cat_tables    = (const float*)d_in[0];
    const float* cont_w        = (const float*)d_in[1];
    const float* cont_b        = (const float*)d_in[2];
    const float* txn_w         = (const float*)d_in[3];
    const float* txn_b         = (const float*)d_in[4];
    const float* txn_feats     = (const float*)d_in[5];
    const float* cont_values   = (const float*)d_in[6];
    const int*   cat_type_ids  = (const int*)d_in[7];
    const int*   cat_value_ids = (const int*)d_in[8];
    const int*   cont_type_ids = (const int*)d_in[9];
    float* out = (float*)d_out;
    unsigned short* btx = (unsigned short*)d_ws;   // 96 KB swizzled B image

    bt_kernel<<<HID, KP, 0, stream>>>(txn_w, btx);
    txn_bstat_kernel<<<TBLK, 256, 0, stream>>>(txn_feats, btx, txn_b, out);
    catcont_kernel<<<CAT_BLOCKS + CONT_BLOCKS, 256, 0, stream>>>(
        cat_tables, cat_type_ids, cat_value_ids,
        cont_w, cont_b, cont_values, cont_type_ids, out);
}